// Round 2
// baseline (294.139 us; speedup 1.0000x reference)
//
#include <hip/hip_runtime.h>
#include <hip/hip_bf16.h>

// Problem constants (B, N, D fixed by the reference)
#define B_ 32
#define N_ 4096
#define D_ 256
#define K_ 2048            // max(1, int(N * (1 - 0.5)))
#define RANK_THREADS 512   // 8 waves; each block ranks 512 of 4096 elements
#define SLICES 8           // N_ / RANK_THREADS

// ---------------------------------------------------------------------------
// Kernel 1: rank-by-counting (replaces bitonic sort).
// Key = (orderable(f32 noisy) << 32) | ~index  -> strictly unique; larger key
// = higher score, ties broken by LOWER index (matches lax.top_k order).
// rank(i) = #{j : key_j > key_i};  sortedIdx[b][rank] = i  gives the full
// descending permutation. Grid (SLICES, B_) = 256 blocks -> one per CU.
// Each block recomputes the full key row into LDS (cheap, ~2K cycles) and
// ranks its slice of 512 elements via broadcast LDS reads (conflict-free).
// Also zeroes the mean accumulator (slice-0 blocks).
// ---------------------------------------------------------------------------
__global__ __launch_bounds__(RANK_THREADS) void rank_kernel(
    const float* __restrict__ attn, const float* __restrict__ noise,
    int* __restrict__ sortedIdx, float* __restrict__ meanAccum) {
  __shared__ unsigned long long keys[N_];  // 32 KiB
  const int b = blockIdx.y;
  const int slice = blockIdx.x;
  const int tid = threadIdx.x;

  // --- compute noisy scores, mirroring the reference f32 op order ---
  for (int i = tid; i < N_; i += RANK_THREADS) {
    float u = noise[b * N_ + i];
    float a = attn[b * N_ + i];
    float x = __fadd_rn(u, 1e-10f);              // u + 1e-10
    float l1 = (float)log((double)x);            // ~correctly-rounded f32 log
    float inner = __fadd_rn(-l1, 1e-10f);        // -log(u+1e-10) + 1e-10
    float g = -(float)log((double)inner);        // gumbel
    float noisy = __fadd_rn(a, __fmul_rn(0.1f, g));  // attn + 0.1*g (no FMA)
    unsigned int fb = __float_as_uint(noisy);
    fb = (fb & 0x80000000u) ? ~fb : (fb | 0x80000000u);  // orderable f32
    keys[i] = ((unsigned long long)fb << 32) | (unsigned int)(~i);
  }
  __syncthreads();

  // --- count keys greater than mine; all lanes read same LDS addr (bcast) ---
  const int i = slice * RANK_THREADS + tid;
  const unsigned long long mine = keys[i];
  const ulonglong2* k2 = (const ulonglong2*)keys;
  unsigned int cnt = 0;
#pragma unroll 16
  for (int j = 0; j < N_ / 2; ++j) {
    ulonglong2 o = k2[j];
    cnt += (o.x > mine) ? 1u : 0u;
    cnt += (o.y > mine) ? 1u : 0u;
  }

  // position cnt in descending order gets index i
  sortedIdx[b * N_ + (int)cnt] = i;

  // zero the mean accumulator (ws is poisoned 0xAA each launch)
  if (slice == 0 && tid < D_) meanAccum[b * D_ + tid] = 0.0f;
}

// ---------------------------------------------------------------------------
// Kernel 2: accumulate sum of pruned rows into meanAccum[b][d].
// Grid (16 chunks, 32 batches), 256 threads. Each block: 128 pruned rows,
// float4 coalesced loads, LDS reduce over 4 row-groups, 4 atomicAdds.
// ---------------------------------------------------------------------------
__global__ __launch_bounds__(256) void mean_kernel(
    const float* __restrict__ seq, const int* __restrict__ sortedIdx,
    float* __restrict__ meanAccum) {
  const int b = blockIdx.y;
  const int chunk = blockIdx.x;           // 0..15
  const int tid = threadIdx.x;
  const int dv = tid & 63;                // float4 column 0..63
  const int sub = tid >> 6;               // row subgroup 0..3
  const int base = b * N_ + K_ + chunk * 128;

  float4 acc = make_float4(0.f, 0.f, 0.f, 0.f);
  for (int r = sub; r < 128; r += 4) {
    int idx = sortedIdx[base + r];
    const float4* row = (const float4*)(seq + ((size_t)b * N_ + idx) * D_);
    float4 v = row[dv];
    acc.x += v.x; acc.y += v.y; acc.z += v.z; acc.w += v.w;
  }

  __shared__ float4 red[4][64];
  red[sub][dv] = acc;
  __syncthreads();
  if (sub == 0) {
    float4 s0 = red[0][dv], s1 = red[1][dv], s2 = red[2][dv], s3 = red[3][dv];
    float sx = s0.x + s1.x + s2.x + s3.x;
    float sy = s0.y + s1.y + s2.y + s3.y;
    float sz = s0.z + s1.z + s2.z + s3.z;
    float sw = s0.w + s1.w + s2.w + s3.w;
    float* dst = meanAccum + b * D_ + dv * 4;
    atomicAdd(dst + 0, sx);
    atomicAdd(dst + 1, sy);
    atomicAdd(dst + 2, sz);
    atomicAdd(dst + 3, sw);
  }
}

// ---------------------------------------------------------------------------
// Kernel 3: out[b][j][d] = seq[b][top_idx[b][j]][d] + 0.05 * (sum[b][d]/2048)
// One float4 per thread; flat thread id == flat float4 output index.
// ---------------------------------------------------------------------------
__global__ __launch_bounds__(256) void out_kernel(
    const float* __restrict__ seq, const int* __restrict__ sortedIdx,
    const float* __restrict__ meanAccum, float* __restrict__ out) {
  const unsigned int t = blockIdx.x * 256u + threadIdx.x;  // < B*K*D/4 = 4194304
  const int dv = t & 63;                 // float4 column
  const int j = (t >> 6) & (K_ - 1);     // rank within top-k
  const int b = t >> 17;                 // batch

  int idx = sortedIdx[b * N_ + j];
  float4 v = ((const float4*)(seq + ((size_t)b * N_ + idx) * D_))[dv];
  float4 m = ((const float4*)(meanAccum + b * D_))[dv];
  const float inv_cnt = 1.0f / 2048.0f;  // count = 2048 (+1e-10 is sub-ulp)
  float4 o;
  o.x = v.x + 0.05f * (m.x * inv_cnt);
  o.y = v.y + 0.05f * (m.y * inv_cnt);
  o.z = v.z + 0.05f * (m.z * inv_cnt);
  o.w = v.w + 0.05f * (m.w * inv_cnt);
  ((float4*)out)[t] = o;
}

// ---------------------------------------------------------------------------
extern "C" void kernel_launch(void* const* d_in, const int* in_sizes, int n_in,
                              void* d_out, int out_size, void* d_ws, size_t ws_size,
                              hipStream_t stream) {
  const float* seq  = (const float*)d_in[0];
  const float* attn = (const float*)d_in[1];
  const float* nois = (const float*)d_in[2];
  float* out = (float*)d_out;

  int* sortedIdx   = (int*)d_ws;                                  // B*N int  = 512 KiB
  float* meanAccum = (float*)((char*)d_ws + (size_t)B_ * N_ * 4); // B*D f32  = 32 KiB

  rank_kernel<<<dim3(SLICES, B_), RANK_THREADS, 0, stream>>>(attn, nois, sortedIdx, meanAccum);
  mean_kernel<<<dim3(16, B_), 256, 0, stream>>>(seq, sortedIdx, meanAccum);
  const int total4 = B_ * K_ * (D_ / 4);   // 4,194,304
  out_kernel<<<total4 / 256, 256, 0, stream>>>(seq, sortedIdx, meanAccum, out);
}

// Round 3
// 291.444 us; speedup vs baseline: 1.0092x; 1.0092x over previous
//
#include <hip/hip_runtime.h>
#include <hip/hip_bf16.h>

// Problem constants (B, N, D fixed by the reference)
#define B_ 32
#define N_ 4096
#define D_ 256
#define K_ 2048            // max(1, int(N * (1 - 0.5)))
#define JC_ 8              // j-chunks per batch row
#define JCHUNK (N_ / JC_)  // 512 keys per chunk
#define CNT_THREADS 512
#define M_ 8               // elements ranked per thread (512*8 = 4096)

typedef unsigned long long u64;
typedef unsigned int u32;

// ---------------------------------------------------------------------------
// Kernel 1: compute sort keys once; zero rank counters and mean accumulator.
// Key = (orderable(f32 noisy) << 32) | ~index  -> strictly unique; larger key
// = higher score, ties broken by LOWER index (matches lax.top_k order).
// ---------------------------------------------------------------------------
__global__ __launch_bounds__(256) void key_kernel(
    const float* __restrict__ attn, const float* __restrict__ noise,
    u64* __restrict__ keys, u32* __restrict__ count,
    float* __restrict__ meanAccum) {
  const int t = blockIdx.x * 256 + threadIdx.x;   // < B*N = 131072
  const int i = t & (N_ - 1);

  float u = noise[t];
  float a = attn[t];
  float x = __fadd_rn(u, 1e-10f);                // u + 1e-10
  float l1 = (float)log((double)x);              // ~correctly-rounded f32 log
  float inner = __fadd_rn(-l1, 1e-10f);          // -log(u+1e-10) + 1e-10
  float g = -(float)log((double)inner);          // gumbel
  float noisy = __fadd_rn(a, __fmul_rn(0.1f, g)); // attn + 0.1*g (no FMA)
  unsigned int fb = __float_as_uint(noisy);
  fb = (fb & 0x80000000u) ? ~fb : (fb | 0x80000000u);  // orderable f32
  keys[t] = ((u64)fb << 32) | (u32)(~i);

  count[t] = 0u;                                  // ws is poisoned each launch
  if (t < B_ * D_) meanAccum[t] = 0.0f;
}

// ---------------------------------------------------------------------------
// Kernel 2: partial rank counts. Grid (JC_, B_) = 256 blocks, 512 threads.
// Block stages its 512-key j-chunk in LDS (4 KiB). Each thread holds M_=8
// "mine" keys in VGPRs and streams the chunk via broadcast ds_read_b128:
// 16 u64-compares amortize each LDS read -> VALU-bound (~14 us chip floor).
// rank(i) = #{j : key_j > key_i}, accumulated with atomics across j-chunks.
// ---------------------------------------------------------------------------
__global__ __launch_bounds__(CNT_THREADS) void count_kernel(
    const u64* __restrict__ keys, u32* __restrict__ count) {
  __shared__ u64 jk[JCHUNK];
  const int b = blockIdx.y;
  const int jc = blockIdx.x;
  const int tid = threadIdx.x;
  const u64* row = keys + b * N_;

  jk[tid] = row[jc * JCHUNK + tid];

  u64 mine[M_];
  u32 cnt[M_];
#pragma unroll
  for (int m = 0; m < M_; ++m) {
    mine[m] = row[m * CNT_THREADS + tid];
    cnt[m] = 0u;
  }
  __syncthreads();

  const ulonglong2* k2 = (const ulonglong2*)jk;
#pragma unroll 4
  for (int j = 0; j < JCHUNK / 2; ++j) {
    ulonglong2 o = k2[j];           // broadcast read: all lanes same address
#pragma unroll
    for (int m = 0; m < M_; ++m) {
      cnt[m] += (o.x > mine[m]) ? 1u : 0u;
      cnt[m] += (o.y > mine[m]) ? 1u : 0u;
    }
  }

  u32* crow = count + b * N_;
#pragma unroll
  for (int m = 0; m < M_; ++m) atomicAdd(crow + m * CNT_THREADS + tid, cnt[m]);
}

// ---------------------------------------------------------------------------
// Kernel 3: mean of pruned rows, iterating by source row i (sequential reads).
// Grid (16 chunks, 32 batches) x 256 thr; each block scans 256 consecutive
// rows, accumulates those with rank >= K. LDS reduce + 4 float4 atomicAdds.
// ---------------------------------------------------------------------------
__global__ __launch_bounds__(256) void mean_kernel(
    const float* __restrict__ seq, const u32* __restrict__ count,
    float* __restrict__ meanAccum) {
  const int b = blockIdx.y;
  const int chunk = blockIdx.x;           // 0..15
  const int tid = threadIdx.x;
  const int dv = tid & 63;                // float4 column 0..63
  const int sub = tid >> 6;               // row subgroup 0..3
  const int base = chunk * 256;

  float4 acc = make_float4(0.f, 0.f, 0.f, 0.f);
  for (int r = sub; r < 256; r += 4) {
    int i = base + r;
    if (count[b * N_ + i] >= K_) {        // pruned row
      const float4* rowp = (const float4*)(seq + ((size_t)b * N_ + i) * D_);
      float4 v = rowp[dv];
      acc.x += v.x; acc.y += v.y; acc.z += v.z; acc.w += v.w;
    }
  }

  __shared__ float4 red[4][64];
  red[sub][dv] = acc;
  __syncthreads();
  if (sub == 0) {
    float4 s0 = red[0][dv], s1 = red[1][dv], s2 = red[2][dv], s3 = red[3][dv];
    float sx = s0.x + s1.x + s2.x + s3.x;
    float sy = s0.y + s1.y + s2.y + s3.y;
    float sz = s0.z + s1.z + s2.z + s3.z;
    float sw = s0.w + s1.w + s2.w + s3.w;
    float* dst = meanAccum + b * D_ + dv * 4;
    atomicAdd(dst + 0, sx);
    atomicAdd(dst + 1, sy);
    atomicAdd(dst + 2, sz);
    atomicAdd(dst + 3, sw);
  }
}

// ---------------------------------------------------------------------------
// Kernel 4: output, iterating by source row i (sequential seq reads, 1 KiB-
// granular scatter writes). out[b][rank][d] = seq[b][i][d] + 0.05*mean[b][d]
// for rank < K. One float4 per thread.
// ---------------------------------------------------------------------------
__global__ __launch_bounds__(256) void out_kernel(
    const float* __restrict__ seq, const u32* __restrict__ count,
    const float* __restrict__ meanAccum, float* __restrict__ out) {
  const unsigned int t = blockIdx.x * 256u + threadIdx.x;  // < B*N*64 = 8388608
  const int dv = t & 63;                 // float4 column
  const int i = (t >> 6) & (N_ - 1);     // source row
  const int b = t >> 18;                 // batch

  u32 r = count[b * N_ + i];             // wave-uniform per 64-lane row group
  if (r < K_) {
    float4 v = ((const float4*)(seq + ((size_t)b * N_ + i) * D_))[dv];
    float4 m = ((const float4*)(meanAccum + b * D_))[dv];
    const float c = 0.05f / 2048.0f;     // MIXUP_ALPHA / count (+1e-10 sub-ulp)
    float4 o;
    o.x = v.x + c * m.x;
    o.y = v.y + c * m.y;
    o.z = v.z + c * m.z;
    o.w = v.w + c * m.w;
    ((float4*)out)[((size_t)b * K_ + r) * 64 + dv] = o;
  }
}

// ---------------------------------------------------------------------------
extern "C" void kernel_launch(void* const* d_in, const int* in_sizes, int n_in,
                              void* d_out, int out_size, void* d_ws, size_t ws_size,
                              hipStream_t stream) {
  const float* seq  = (const float*)d_in[0];
  const float* attn = (const float*)d_in[1];
  const float* nois = (const float*)d_in[2];
  float* out = (float*)d_out;

  u64* keys        = (u64*)d_ws;                                   // 1 MiB
  u32* count       = (u32*)((char*)d_ws + (size_t)B_ * N_ * 8);    // 512 KiB
  float* meanAccum = (float*)((char*)d_ws + (size_t)B_ * N_ * 12); // 32 KiB

  key_kernel<<<(B_ * N_) / 256, 256, 0, stream>>>(attn, nois, keys, count, meanAccum);
  count_kernel<<<dim3(JC_, B_), CNT_THREADS, 0, stream>>>(keys, count);
  mean_kernel<<<dim3(16, B_), 256, 0, stream>>>(seq, count, meanAccum);
  const int totalT = B_ * N_ * 64;       // 8,388,608 float4 slots
  out_kernel<<<totalT / 256, 256, 0, stream>>>(seq, count, meanAccum, out);
}

// Round 5
// 283.677 us; speedup vs baseline: 1.0369x; 1.0274x over previous
//
#include <hip/hip_runtime.h>
#include <hip/hip_bf16.h>

// Problem constants (B, N, D fixed by the reference)
#define B_ 32
#define N_ 4096
#define D_ 256
#define K_ 2048            // max(1, int(N * (1 - 0.5)))
#define JC_ 8              // j-chunks per batch row
#define JCHUNK (N_ / JC_)  // 512 keys per chunk
#define CNT_THREADS 512
#define M_ 8               // elements ranked per thread (512*8 = 4096)

typedef unsigned long long u64;
typedef unsigned int u32;
// Native vector type: legal operand for __builtin_nontemporal_load/store
// (HIP_vector_type float4 is a struct and is rejected by the builtin).
typedef float f4 __attribute__((ext_vector_type(4)));

// ---------------------------------------------------------------------------
// Kernel 1: compute sort keys once; zero rank counters and mean accumulator.
// Key = (orderable(f32 noisy) << 32) | ~index  -> strictly unique; larger key
// = higher score, ties broken by LOWER index (matches lax.top_k order).
// ---------------------------------------------------------------------------
__global__ __launch_bounds__(256) void key_kernel(
    const float* __restrict__ attn, const float* __restrict__ noise,
    u64* __restrict__ keys, u32* __restrict__ count,
    float* __restrict__ meanAccum) {
  const int t = blockIdx.x * 256 + threadIdx.x;   // < B*N = 131072
  const int i = t & (N_ - 1);

  float u = noise[t];
  float a = attn[t];
  float x = __fadd_rn(u, 1e-10f);                // u + 1e-10
  float l1 = (float)log((double)x);              // ~correctly-rounded f32 log
  float inner = __fadd_rn(-l1, 1e-10f);          // -log(u+1e-10) + 1e-10
  float g = -(float)log((double)inner);          // gumbel
  float noisy = __fadd_rn(a, __fmul_rn(0.1f, g)); // attn + 0.1*g (no FMA)
  unsigned int fb = __float_as_uint(noisy);
  fb = (fb & 0x80000000u) ? ~fb : (fb | 0x80000000u);  // orderable f32
  keys[t] = ((u64)fb << 32) | (u32)(~i);

  count[t] = 0u;                                  // ws is poisoned each launch
  if (t < B_ * D_) meanAccum[t] = 0.0f;
}

// ---------------------------------------------------------------------------
// Kernel 2: partial rank counts. Grid (JC_, B_) = 256 blocks, 512 threads.
// Block stages its 512-key j-chunk in LDS (4 KiB). Each thread holds M_=8
// "mine" keys in VGPRs and streams the chunk via broadcast ds_read_b128:
// 16 u64-compares amortize each LDS read -> VALU-bound (~14 us chip floor).
// rank(i) = #{j : key_j > key_i}, accumulated with atomics across j-chunks.
// ---------------------------------------------------------------------------
__global__ __launch_bounds__(CNT_THREADS) void count_kernel(
    const u64* __restrict__ keys, u32* __restrict__ count) {
  __shared__ u64 jk[JCHUNK];
  const int b = blockIdx.y;
  const int jc = blockIdx.x;
  const int tid = threadIdx.x;
  const u64* row = keys + b * N_;

  jk[tid] = row[jc * JCHUNK + tid];

  u64 mine[M_];
  u32 cnt[M_];
#pragma unroll
  for (int m = 0; m < M_; ++m) {
    mine[m] = row[m * CNT_THREADS + tid];
    cnt[m] = 0u;
  }
  __syncthreads();

  const ulonglong2* k2 = (const ulonglong2*)jk;
#pragma unroll 4
  for (int j = 0; j < JCHUNK / 2; ++j) {
    ulonglong2 o = k2[j];           // broadcast read: all lanes same address
#pragma unroll
    for (int m = 0; m < M_; ++m) {
      cnt[m] += (o.x > mine[m]) ? 1u : 0u;
      cnt[m] += (o.y > mine[m]) ? 1u : 0u;
    }
  }

  u32* crow = count + b * N_;
#pragma unroll
  for (int m = 0; m < M_; ++m) atomicAdd(crow + m * CNT_THREADS + tid, cnt[m]);
}

// ---------------------------------------------------------------------------
// Kernel 3: mean of pruned rows, iterating by source row i (sequential reads).
// Grid (16 chunks, 32 batches) x 256 thr; each block scans 256 consecutive
// rows, accumulates those with rank >= K. Non-temporal seq loads (single-use
// stream). LDS reduce + 4 float atomicAdds per lane.
// ---------------------------------------------------------------------------
__global__ __launch_bounds__(256) void mean_kernel(
    const float* __restrict__ seq, const u32* __restrict__ count,
    float* __restrict__ meanAccum) {
  const int b = blockIdx.y;
  const int chunk = blockIdx.x;           // 0..15
  const int tid = threadIdx.x;
  const int dv = tid & 63;                // float4 column 0..63
  const int sub = tid >> 6;               // row subgroup 0..3
  const int base = chunk * 256;

  f4 acc = (f4)(0.0f);
  for (int r = sub; r < 256; r += 4) {
    int i = base + r;
    if (count[b * N_ + i] >= K_) {        // pruned row (wave-uniform branch)
      const f4* rowp = (const f4*)(seq + ((size_t)b * N_ + i) * D_);
      f4 v = __builtin_nontemporal_load(rowp + dv);
      acc += v;
    }
  }

  __shared__ f4 red[4][64];
  red[sub][dv] = acc;
  __syncthreads();
  if (sub == 0) {
    f4 s = red[0][dv] + red[1][dv] + red[2][dv] + red[3][dv];
    float* dst = meanAccum + b * D_ + dv * 4;
    atomicAdd(dst + 0, s.x);
    atomicAdd(dst + 1, s.y);
    atomicAdd(dst + 2, s.z);
    atomicAdd(dst + 3, s.w);
  }
}

// ---------------------------------------------------------------------------
// Kernel 4: output, iterating by source row i (sequential seq reads, 1 KiB-
// granular coalesced scatter writes). out[b][rank][d] = seq[b][i][d] +
// 0.05*mean[b][d] for rank < K. One float4 per thread; NT load/store on the
// single-use streams.
// ---------------------------------------------------------------------------
__global__ __launch_bounds__(256) void out_kernel(
    const float* __restrict__ seq, const u32* __restrict__ count,
    const float* __restrict__ meanAccum, float* __restrict__ out) {
  const unsigned int t = blockIdx.x * 256u + threadIdx.x;  // < B*N*64 = 8388608
  const int dv = t & 63;                 // float4 column
  const int i = (t >> 6) & (N_ - 1);     // source row
  const int b = t >> 18;                 // batch

  u32 r = count[b * N_ + i];             // wave-uniform per 64-lane row group
  if (r < K_) {
    const f4* rowp = (const f4*)(seq + ((size_t)b * N_ + i) * D_);
    f4 v = __builtin_nontemporal_load(rowp + dv);
    f4 m = ((const f4*)(meanAccum + b * D_))[dv];
    const float c = 0.05f / 2048.0f;     // MIXUP_ALPHA / count (+1e-10 sub-ulp)
    f4 o = v + c * m;
    __builtin_nontemporal_store(o, ((f4*)out) + ((size_t)b * K_ + r) * 64 + dv);
  }
}

// ---------------------------------------------------------------------------
extern "C" void kernel_launch(void* const* d_in, const int* in_sizes, int n_in,
                              void* d_out, int out_size, void* d_ws, size_t ws_size,
                              hipStream_t stream) {
  const float* seq  = (const float*)d_in[0];
  const float* attn = (const float*)d_in[1];
  const float* nois = (const float*)d_in[2];
  float* out = (float*)d_out;

  u64* keys        = (u64*)d_ws;                                   // 1 MiB
  u32* count       = (u32*)((char*)d_ws + (size_t)B_ * N_ * 8);    // 512 KiB
  float* meanAccum = (float*)((char*)d_ws + (size_t)B_ * N_ * 12); // 32 KiB

  key_kernel<<<(B_ * N_) / 256, 256, 0, stream>>>(attn, nois, keys, count, meanAccum);
  count_kernel<<<dim3(JC_, B_), CNT_THREADS, 0, stream>>>(keys, count);
  mean_kernel<<<dim3(16, B_), 256, 0, stream>>>(seq, count, meanAccum);
  const int totalT = B_ * N_ * 64;       // 8,388,608 float4 slots
  out_kernel<<<totalT / 256, 256, 0, stream>>>(seq, count, meanAccum, out);
}